// Round 21
// baseline (78.086 us; speedup 1.0000x reference)
//
#include <hip/hip_runtime.h>
#include <hip/hip_bf16.h>
#include <math.h>

// Leapfrog on SPD(32), eigh-free, inverse-free, barrier-free MFMA version.
//   U = S·P ; Ut = P·S (independent) ; H = U·U (= S·P·S·P = S·G)
//   M = 0.02·U - 2e-4·H  (= 2DT·S·pi_half)
//   E = exp(M^T) Taylor-3 (X3 = I + M/3 in f32 VALU; 2 MFMA stages with
//   +I applied as VALU diagonal adds — no persistent identity fragment)
//   Sigma_new = sym(S·E) + 1e-8 I
// R20 with CACHED stores (NT removed): out rows stride 4108 B (not 128B-
// aligned), so every NT store wrote partial lines at segment boundaries —
// NT bypasses L2 line-assembly, forcing memory-side read-modify-write
// (WRITE_SIZE 146 vs 134.6 MB ideal). Cached stores let L2 assemble full
// lines across adjacent matrices' contiguous blocks. Last untested lever;
// occupancy levers are exhausted (residency pinned ~12 waves/CU across
// VGPR 44-68, LDS 17-68KB, block 256/1024 — not a static resource).
// LDS bounce keeps the MANDATORY __threadfence_block() (R15-class race:
// bounce reads consume other lanes' writes, invisible to per-thread alias
// analysis; DS pipe in-order per wave so pinned order suffices).
// All validated pieces: trunc v_perm packs, LDS-bounce sym epilogue with
// contiguous stores, cached loads (L3 serves ~half of replay re-reads),
// U^2-head, Taylor-3 f32 first stage, v_permlane32_swap_b32 exchange
// (swap32(x,y): x.lanes[32:63] <-> y.lanes[0:31]), no setprio, no
// launch-bounds cap, 256-thread blocks, one matrix per wave (all
// multi-matrix/persistent/big-block variants measured worse, R7-R19).

typedef unsigned int u32;
typedef __attribute__((ext_vector_type(8))) short bf16x8;
typedef __attribute__((ext_vector_type(16))) float f32x16;

#define FPAD 33   // f32 row stride of sym buffer: 33 mod 32 == 1 -> conflict-free

union U4 { u32 u[4]; bf16x8 v; };

__device__ __forceinline__ bf16x8 mk8(u32 a, u32 b, u32 c, u32 d) {
    U4 t; t.u[0] = a; t.u[1] = b; t.u[2] = c; t.u[3] = d; return t.v;
}

// pack bf16(x),bf16(y) (truncated) into one u32: low16 = x, high16 = y
__device__ __forceinline__ u32 pkt(float x, float y) {
    return __builtin_amdgcn_perm(__float_as_uint(y), __float_as_uint(x), 0x07060302u);
}

__device__ __forceinline__ float asfloat(u32 b) {
    union { u32 u; float f; } c; c.u = b; return c.f;
}

__device__ __forceinline__ f32x16 zero16() {
    f32x16 z;
#pragma unroll
    for (int i = 0; i < 16; ++i) z[i] = 0.f;
    return z;
}

// D-layout row of acc element i for this lane: (i&3) + 8*(i>>2) + 4*h; col = fr.
__device__ __forceinline__ float diagf(int i, int h, int fr) {
    return (((i & 3) + 8 * (i >> 2) + 4 * h) == fr) ? 1.f : 0.f;
}

struct Frag8 { u32 r[8]; };

// v_permlane32_swap_b32: x.lanes[32:63] <-> y.lanes[0:31]
__device__ __forceinline__ void swap32(u32& x, u32& y) {
    asm("v_permlane32_swap_b32 %0, %1" : "+v"(x), "+v"(y));
}

// packed-pair regs p[8] (D-layout pairs) -> B-fragment order.
__device__ __forceinline__ void xchg(const u32* p, Frag8& B) {
    { u32 x = p[0], y = p[2]; swap32(x, y); B.r[0] = x; B.r[2] = y; }
    { u32 x = p[1], y = p[3]; swap32(x, y); B.r[1] = x; B.r[3] = y; }
    { u32 x = p[4], y = p[6]; swap32(x, y); B.r[4] = x; B.r[6] = y; }
    { u32 x = p[5], y = p[7]; swap32(x, y); B.r[5] = x; B.r[7] = y; }
}

__device__ __forceinline__ void bconv(const f32x16& X, Frag8& B) {
    u32 p[8];
#pragma unroll
    for (int i = 0; i < 8; ++i) p[i] = pkt(X[2*i], X[2*i+1]);
    xchg(p, B);
}

__device__ __forceinline__ void bconv_s(const f32x16& X, float scale, Frag8& B) {
    u32 p[8];
#pragma unroll
    for (int i = 0; i < 8; ++i) p[i] = pkt(X[2*i] * scale, X[2*i+1] * scale);
    xchg(p, B);
}

__device__ __forceinline__ void bconv_split(const f32x16& X, Frag8& Bh, Frag8& Bl) {
    u32 p[8], q[8];
#pragma unroll
    for (int i = 0; i < 8; ++i) {
        const float x = X[2*i], y = X[2*i+1];
        p[i] = pkt(x, y);
        const float lx = x - asfloat(p[i] << 16);
        const float ly = y - asfloat(p[i] & 0xffff0000u);
        q[i] = pkt(lx, ly);
    }
    xchg(p, Bh);
    xchg(q, Bl);
}

__device__ __forceinline__ f32x16 MFMA1(const u32* a, const u32* b, f32x16 acc) {
    return __builtin_amdgcn_mfma_f32_32x32x16_bf16(
        mk8(a[0], a[1], a[2], a[3]), mk8(b[0], b[1], b[2], b[3]), acc, 0, 0, 0);
}

__device__ __forceinline__ f32x16 matmul(const Frag8& A, const Frag8& B, f32x16 acc) {
    acc = MFMA1(A.r,     B.r,     acc);   // k = 0..15
    acc = MFMA1(A.r + 4, B.r + 4, acc);   // k = 16..31
    return acc;
}

__global__ __launch_bounds__(256)
void leapfrog_fused(const float* __restrict__ Sg, const float* __restrict__ Pg,
                    const float* __restrict__ phig, const float* __restrict__ piphig,
                    float* __restrict__ out, int total)
{
    __shared__ __align__(16) float symb[4 * 32 * FPAD];

    const int w  = threadIdx.x >> 6;
    const int l  = threadIdx.x & 63;
    const int bn = blockIdx.x * 4 + w;
    if (bn >= total) return;            // wave-uniform; kernel has no barriers

    float* sy = symb + w * 32 * FPAD;

    const int fr = l & 31;
    const int h  = l >> 5;
    const size_t gbase = (size_t)bn * 1024;

    // ---- fragment loads straight from global; phi prefetched alongside ----
    const float* Srow = Sg + gbase + fr * 32 + h * 8;
    const float* Prow = Pg + gbase + fr * 32 + h * 8;
    const float4 sv[4] = { *(const float4*)(Srow +  0), *(const float4*)(Srow +  4),
                           *(const float4*)(Srow + 16), *(const float4*)(Srow + 20) };
    const float4 pv[4] = { *(const float4*)(Prow +  0), *(const float4*)(Prow +  4),
                           *(const float4*)(Prow + 16), *(const float4*)(Prow + 20) };
    // phi inputs: lanes 0-2 each handle one component in the epilogue
    float phc = 0.f, qhc = 0.f;
    if (l < 3) { phc = phig[3 * bn + l]; qhc = piphig[3 * bn + l]; }

    Frag8 FS, FSl, FP;
#pragma unroll
    for (int i = 0; i < 4; ++i) {
        const float4 s = sv[i];
        const float4 p = pv[i];
        const u32 ha = pkt(s.x, s.y);
        const u32 hb = pkt(s.z, s.w);
        FS.r[2*i]   = ha;
        FS.r[2*i+1] = hb;
        const float lx = s.x - asfloat(ha << 16);
        const float ly = s.y - asfloat(ha & 0xffff0000u);
        const float lz = s.z - asfloat(hb << 16);
        const float lw = s.w - asfloat(hb & 0xffff0000u);
        FSl.r[2*i]   = pkt(lx, ly);
        FSl.r[2*i+1] = pkt(lz, lw);
        FP.r[2*i]   = pkt(p.x, p.y);
        FP.r[2*i+1] = pkt(p.z, p.w);
    }

    // ---- U = S·P ; Ut = P·S (independent chains) ; H = U·U = S·P·S·P ----
    f32x16 U  = matmul(FS, FP, zero16());
    f32x16 Ut = matmul(FP, FS, zero16());
    Frag8 BU;  bconv(U,  BU);
    Frag8 BUt; bconv(Ut, BUt);              // as A-operand represents U
    f32x16 H = matmul(BUt, BU, zero16());

    // ---- M = 2DT·U − 2DT²·H ;  X3 = I + M/3 (f32 VALU, diag inline) ----
    f32x16 M, X;
#pragma unroll
    for (int i = 0; i < 16; ++i) {
        M[i] = 0.02f * U[i] - 2e-4f * H[i];
        X[i] = diagf(i, h, fr) + (1.0f / 3.0f) * M[i];
    }
    Frag8 FM; bconv(M, FM);                 // A-frag of M^T

    // ---- X2 = I + (1/2)·M^T·X3 ; X1 = I + M^T·X2 ----
    {
        Frag8 BX; bconv_s(X, 0.5f, BX);
        X = matmul(FM, BX, zero16());
#pragma unroll
        for (int i = 0; i < 16; ++i) X[i] += diagf(i, h, fr);
    }
    {
        Frag8 BX; bconv(X, BX);
        X = matmul(FM, BX, zero16());
#pragma unroll
        for (int i = 0; i < 16; ++i) X[i] += diagf(i, h, fr);
    }

    // ---- Y^T = S·X, hi/lo split, ONE serial accumulator ----
    Frag8 BE, BEl;
    bconv_split(X, BE, BEl);
    f32x16 Y = matmul(FS,  BEl, zero16());
    Y        = matmul(FSl, BE,  Y);
    Y        = matmul(FS,  BE,  Y);

    // ---- sym + eps·I via LDS bounce (fence REQUIRED — R15-class race) ----
#pragma unroll
    for (int i = 0; i < 16; ++i) {
        const int r = (i & 3) + 8 * (i >> 2) + 4 * h;
        sy[r * FPAD + fr] = Y[i];
    }
    __threadfence_block();                  // order bounce writes before reads
    const size_t obase = (size_t)bn * 1027;
#pragma unroll
    for (int k = 0; k < 16; ++k) {
        const int idx = k * 64 + l;
        const int r = idx >> 5, c = idx & 31;
        const float a = sy[r * FPAD + c];
        const float b = sy[c * FPAD + r];
        float v = 0.5f * (a + b);
        if (r == c) v += 1e-8f;
        out[obase + idx] = v;               // cached store: L2 assembles lines
    }

    // ---- fused phi retraction (lanes 0-2, double; floor-based mod 2pi) ----
    if (l < 3) {
        const double TWO_PI = 6.283185307179586476925287;
        const double PI_    = 3.141592653589793238462643;
        const double c0 = (double)__shfl(phc, 0, 64) + 0.01 * (double)__shfl(qhc, 0, 64);
        const double c1 = (double)__shfl(phc, 1, 64) + 0.01 * (double)__shfl(qhc, 1, 64);
        const double c2 = (double)__shfl(phc, 2, 64) + 0.01 * (double)__shfl(qhc, 2, 64);
        const double me = (l == 0) ? c0 : (l == 1) ? c1 : c2;
        const double theta = sqrt(c0 * c0 + c1 * c1 + c2 * c2);
        const double ts = theta > 1e-12 ? theta : 1e-12;
        const double k2 = floor(theta * (1.0 / TWO_PI));
        const double tw = theta - k2 * TWO_PI;          // fmod(theta, 2pi), theta >= 0
        double t, sgn;
        if (tw > PI_) { t = TWO_PI - tw; sgn = -1.0; }
        else          { t = tw;          sgn = 1.0;  }
        const double rmax = PI_ - 0.01;
        if (t > rmax) t = rmax;
        const double f = sgn * t / ts;
        out[obase + 1024 + l] = (float)(me * f);
    }
}

extern "C" void kernel_launch(void* const* d_in, const int* in_sizes, int n_in,
                              void* d_out, int out_size, void* d_ws, size_t ws_size,
                              hipStream_t stream)
{
    const float* Sg     = (const float*)d_in[0];
    const float* Pg     = (const float*)d_in[1];
    const float* phig   = (const float*)d_in[2];
    const float* piphig = (const float*)d_in[3];
    float* out = (float*)d_out;

    const int total = in_sizes[0] / 1024;   // B*N = 32768 matrices

    leapfrog_fused<<<(total + 3) / 4, 256, 0, stream>>>(Sg, Pg, phig, piphig, out, total);
}

// Round 22
// 68.206 us; speedup vs baseline: 1.1449x; 1.1449x over previous
//
#include <hip/hip_runtime.h>
#include <hip/hip_bf16.h>
#include <math.h>

// Leapfrog on SPD(32), eigh-free, inverse-free, barrier-free MFMA version.
//   U = S·P ; Ut = P·S (independent) ; H = U·U (= S·P·S·P = S·G)
//   M = 0.02·U - 2e-4·H  (= 2DT·S·pi_half)
//   E = exp(M^T) Taylor-3 (X3 = I + M/3 in f32 VALU; 2 MFMA stages with
//   +I applied as VALU diagonal adds — no persistent identity fragment)
//   Sigma_new = sym(S·E) + 1e-8 I
// FINAL FORM (= R20): one wave per matrix, 256-thread blocks, NT stores.
// R21 A/B proved NT stores are required: cached stores hit ideal
// WRITE_SIZE (132 MB) but evict the replay-resident inputs from L3 ->
// timed run 68.8 -> 78.1 us. NT's +11 MB boundary-RMW write traffic is
// the cheaper side of the trade.
// Structural plateau evidence: residency pinned ~12 waves/CU across VGPR
// 44-88, LDS 17-68KB, block 256/1024 (R7-R20); all bytes-in-flight levers
// (reg prefetch, persistent waves, glds staging) regress via register/
// occupancy side-effects; kernel sits at ~4.0 TB/s effective in a
// latency-queuing equilibrium -> ~69 us floor for this decomposition.
// LDS bounce carries the MANDATORY __threadfence_block() (R15-class race:
// bounce reads consume other lanes' writes, invisible to per-thread alias
// analysis; DS pipe is in-order per wave so pinned order suffices).
// Validated pieces: trunc v_perm packs, LDS-bounce sym epilogue with
// contiguous NT stores, cached loads (L3 serves ~half of replay
// re-reads), U^2-head, Taylor-3 f32 first stage, serial one-accumulator
// tail, v_permlane32_swap_b32 exchange (swap32(x,y): x.lanes[32:63] <->
// y.lanes[0:31]), no setprio, no launch-bounds cap.

typedef unsigned int u32;
typedef __attribute__((ext_vector_type(8))) short bf16x8;
typedef __attribute__((ext_vector_type(16))) float f32x16;

#define FPAD 33   // f32 row stride of sym buffer: 33 mod 32 == 1 -> conflict-free

union U4 { u32 u[4]; bf16x8 v; };

__device__ __forceinline__ bf16x8 mk8(u32 a, u32 b, u32 c, u32 d) {
    U4 t; t.u[0] = a; t.u[1] = b; t.u[2] = c; t.u[3] = d; return t.v;
}

// pack bf16(x),bf16(y) (truncated) into one u32: low16 = x, high16 = y
__device__ __forceinline__ u32 pkt(float x, float y) {
    return __builtin_amdgcn_perm(__float_as_uint(y), __float_as_uint(x), 0x07060302u);
}

__device__ __forceinline__ float asfloat(u32 b) {
    union { u32 u; float f; } c; c.u = b; return c.f;
}

__device__ __forceinline__ f32x16 zero16() {
    f32x16 z;
#pragma unroll
    for (int i = 0; i < 16; ++i) z[i] = 0.f;
    return z;
}

// D-layout row of acc element i for this lane: (i&3) + 8*(i>>2) + 4*h; col = fr.
__device__ __forceinline__ float diagf(int i, int h, int fr) {
    return (((i & 3) + 8 * (i >> 2) + 4 * h) == fr) ? 1.f : 0.f;
}

struct Frag8 { u32 r[8]; };

// v_permlane32_swap_b32: x.lanes[32:63] <-> y.lanes[0:31]
__device__ __forceinline__ void swap32(u32& x, u32& y) {
    asm("v_permlane32_swap_b32 %0, %1" : "+v"(x), "+v"(y));
}

// packed-pair regs p[8] (D-layout pairs) -> B-fragment order.
__device__ __forceinline__ void xchg(const u32* p, Frag8& B) {
    { u32 x = p[0], y = p[2]; swap32(x, y); B.r[0] = x; B.r[2] = y; }
    { u32 x = p[1], y = p[3]; swap32(x, y); B.r[1] = x; B.r[3] = y; }
    { u32 x = p[4], y = p[6]; swap32(x, y); B.r[4] = x; B.r[6] = y; }
    { u32 x = p[5], y = p[7]; swap32(x, y); B.r[5] = x; B.r[7] = y; }
}

__device__ __forceinline__ void bconv(const f32x16& X, Frag8& B) {
    u32 p[8];
#pragma unroll
    for (int i = 0; i < 8; ++i) p[i] = pkt(X[2*i], X[2*i+1]);
    xchg(p, B);
}

__device__ __forceinline__ void bconv_s(const f32x16& X, float scale, Frag8& B) {
    u32 p[8];
#pragma unroll
    for (int i = 0; i < 8; ++i) p[i] = pkt(X[2*i] * scale, X[2*i+1] * scale);
    xchg(p, B);
}

__device__ __forceinline__ void bconv_split(const f32x16& X, Frag8& Bh, Frag8& Bl) {
    u32 p[8], q[8];
#pragma unroll
    for (int i = 0; i < 8; ++i) {
        const float x = X[2*i], y = X[2*i+1];
        p[i] = pkt(x, y);
        const float lx = x - asfloat(p[i] << 16);
        const float ly = y - asfloat(p[i] & 0xffff0000u);
        q[i] = pkt(lx, ly);
    }
    xchg(p, Bh);
    xchg(q, Bl);
}

__device__ __forceinline__ f32x16 MFMA1(const u32* a, const u32* b, f32x16 acc) {
    return __builtin_amdgcn_mfma_f32_32x32x16_bf16(
        mk8(a[0], a[1], a[2], a[3]), mk8(b[0], b[1], b[2], b[3]), acc, 0, 0, 0);
}

__device__ __forceinline__ f32x16 matmul(const Frag8& A, const Frag8& B, f32x16 acc) {
    acc = MFMA1(A.r,     B.r,     acc);   // k = 0..15
    acc = MFMA1(A.r + 4, B.r + 4, acc);   // k = 16..31
    return acc;
}

__global__ __launch_bounds__(256)
void leapfrog_fused(const float* __restrict__ Sg, const float* __restrict__ Pg,
                    const float* __restrict__ phig, const float* __restrict__ piphig,
                    float* __restrict__ out, int total)
{
    __shared__ __align__(16) float symb[4 * 32 * FPAD];

    const int w  = threadIdx.x >> 6;
    const int l  = threadIdx.x & 63;
    const int bn = blockIdx.x * 4 + w;
    if (bn >= total) return;            // wave-uniform; kernel has no barriers

    float* sy = symb + w * 32 * FPAD;

    const int fr = l & 31;
    const int h  = l >> 5;
    const size_t gbase = (size_t)bn * 1024;

    // ---- fragment loads straight from global; phi prefetched alongside ----
    const float* Srow = Sg + gbase + fr * 32 + h * 8;
    const float* Prow = Pg + gbase + fr * 32 + h * 8;
    const float4 sv[4] = { *(const float4*)(Srow +  0), *(const float4*)(Srow +  4),
                           *(const float4*)(Srow + 16), *(const float4*)(Srow + 20) };
    const float4 pv[4] = { *(const float4*)(Prow +  0), *(const float4*)(Prow +  4),
                           *(const float4*)(Prow + 16), *(const float4*)(Prow + 20) };
    // phi inputs: lanes 0-2 each handle one component in the epilogue
    float phc = 0.f, qhc = 0.f;
    if (l < 3) { phc = phig[3 * bn + l]; qhc = piphig[3 * bn + l]; }

    Frag8 FS, FSl, FP;
#pragma unroll
    for (int i = 0; i < 4; ++i) {
        const float4 s = sv[i];
        const float4 p = pv[i];
        const u32 ha = pkt(s.x, s.y);
        const u32 hb = pkt(s.z, s.w);
        FS.r[2*i]   = ha;
        FS.r[2*i+1] = hb;
        const float lx = s.x - asfloat(ha << 16);
        const float ly = s.y - asfloat(ha & 0xffff0000u);
        const float lz = s.z - asfloat(hb << 16);
        const float lw = s.w - asfloat(hb & 0xffff0000u);
        FSl.r[2*i]   = pkt(lx, ly);
        FSl.r[2*i+1] = pkt(lz, lw);
        FP.r[2*i]   = pkt(p.x, p.y);
        FP.r[2*i+1] = pkt(p.z, p.w);
    }

    // ---- U = S·P ; Ut = P·S (independent chains) ; H = U·U = S·P·S·P ----
    f32x16 U  = matmul(FS, FP, zero16());
    f32x16 Ut = matmul(FP, FS, zero16());
    Frag8 BU;  bconv(U,  BU);
    Frag8 BUt; bconv(Ut, BUt);              // as A-operand represents U
    f32x16 H = matmul(BUt, BU, zero16());

    // ---- M = 2DT·U − 2DT²·H ;  X3 = I + M/3 (f32 VALU, diag inline) ----
    f32x16 M, X;
#pragma unroll
    for (int i = 0; i < 16; ++i) {
        M[i] = 0.02f * U[i] - 2e-4f * H[i];
        X[i] = diagf(i, h, fr) + (1.0f / 3.0f) * M[i];
    }
    Frag8 FM; bconv(M, FM);                 // A-frag of M^T

    // ---- X2 = I + (1/2)·M^T·X3 ; X1 = I + M^T·X2 ----
    {
        Frag8 BX; bconv_s(X, 0.5f, BX);
        X = matmul(FM, BX, zero16());
#pragma unroll
        for (int i = 0; i < 16; ++i) X[i] += diagf(i, h, fr);
    }
    {
        Frag8 BX; bconv(X, BX);
        X = matmul(FM, BX, zero16());
#pragma unroll
        for (int i = 0; i < 16; ++i) X[i] += diagf(i, h, fr);
    }

    // ---- Y^T = S·X, hi/lo split, ONE serial accumulator ----
    Frag8 BE, BEl;
    bconv_split(X, BE, BEl);
    f32x16 Y = matmul(FS,  BEl, zero16());
    Y        = matmul(FSl, BE,  Y);
    Y        = matmul(FS,  BE,  Y);

    // ---- sym + eps·I via LDS bounce (fence REQUIRED — R15-class race) ----
#pragma unroll
    for (int i = 0; i < 16; ++i) {
        const int r = (i & 3) + 8 * (i >> 2) + 4 * h;
        sy[r * FPAD + fr] = Y[i];
    }
    __threadfence_block();                  // order bounce writes before reads
    const size_t obase = (size_t)bn * 1027;
#pragma unroll
    for (int k = 0; k < 16; ++k) {
        const int idx = k * 64 + l;
        const int r = idx >> 5, c = idx & 31;
        const float a = sy[r * FPAD + c];
        const float b = sy[c * FPAD + r];
        float v = 0.5f * (a + b);
        if (r == c) v += 1e-8f;
        __builtin_nontemporal_store(v, &out[obase + idx]);
    }

    // ---- fused phi retraction (lanes 0-2, double; floor-based mod 2pi) ----
    if (l < 3) {
        const double TWO_PI = 6.283185307179586476925287;
        const double PI_    = 3.141592653589793238462643;
        const double c0 = (double)__shfl(phc, 0, 64) + 0.01 * (double)__shfl(qhc, 0, 64);
        const double c1 = (double)__shfl(phc, 1, 64) + 0.01 * (double)__shfl(qhc, 1, 64);
        const double c2 = (double)__shfl(phc, 2, 64) + 0.01 * (double)__shfl(qhc, 2, 64);
        const double me = (l == 0) ? c0 : (l == 1) ? c1 : c2;
        const double theta = sqrt(c0 * c0 + c1 * c1 + c2 * c2);
        const double ts = theta > 1e-12 ? theta : 1e-12;
        const double k2 = floor(theta * (1.0 / TWO_PI));
        const double tw = theta - k2 * TWO_PI;          // fmod(theta, 2pi), theta >= 0
        double t, sgn;
        if (tw > PI_) { t = TWO_PI - tw; sgn = -1.0; }
        else          { t = tw;          sgn = 1.0;  }
        const double rmax = PI_ - 0.01;
        if (t > rmax) t = rmax;
        const double f = sgn * t / ts;
        __builtin_nontemporal_store((float)(me * f), &out[obase + 1024 + l]);
    }
}

extern "C" void kernel_launch(void* const* d_in, const int* in_sizes, int n_in,
                              void* d_out, int out_size, void* d_ws, size_t ws_size,
                              hipStream_t stream)
{
    const float* Sg     = (const float*)d_in[0];
    const float* Pg     = (const float*)d_in[1];
    const float* phig   = (const float*)d_in[2];
    const float* piphig = (const float*)d_in[3];
    float* out = (float*)d_out;

    const int total = in_sizes[0] / 1024;   // B*N = 32768 matrices

    leapfrog_fused<<<(total + 3) / 4, 256, 0, stream>>>(Sg, Pg, phig, piphig, out, total);
}

// Round 23
// 67.661 us; speedup vs baseline: 1.1541x; 1.0080x over previous
//
#include <hip/hip_runtime.h>
#include <hip/hip_bf16.h>
#include <math.h>

// Leapfrog on SPD(32), eigh-free, inverse-free, barrier-free MFMA version.
//   U = S·P ; Ut = P·S (independent) ; H = U·U (= S·P·S·P = S·G)
//   M = 0.02·U - 2e-4·H  (= 2DT·S·pi_half)
//   E = exp(M^T) Taylor-3 (X3 = I + M/3 in f32 VALU; 2 MFMA stages with
//   +I applied as VALU diagonal adds — no persistent identity fragment)
//   Sigma_new = sym(S·E) + 1e-8 I
// R22/R20 body + XCD-aware chunked blockIdx swizzle (bijective; only when
// gridDim.x % 8 == 0): default dispatch round-robins consecutive blocks
// across 8 XCDs -> each XCD reads a 16KB-granular stride-128KB gather;
// chunked swizzle gives each XCD one contiguous 1/8 of the inputs ->
// sequential DRAM streams per partition. Blocks share no data, so this is
// a page/stream-locality bet, not L2 reuse. Last zero-cost lever.
// (float4 epilogue stores evaluated and rejected: out stride 1027 floats
// makes 16B alignment bn-dependent -> misaligned x4 stores illegal.)
// NT stores REQUIRED (R21 A/B: cached stores evict replay-resident inputs
// from L3, 68.8 -> 78.1 us). LDS bounce carries the MANDATORY
// __threadfence_block() (R15-class race: bounce reads consume other
// lanes' writes, invisible to per-thread alias analysis; DS pipe is
// in-order per wave so pinned order suffices).
// Validated pieces: trunc v_perm packs, LDS-bounce sym epilogue with
// contiguous NT stores, cached loads (L3 serves ~half of replay
// re-reads), U^2-head, Taylor-3 f32 first stage, serial one-accumulator
// tail, v_permlane32_swap_b32 exchange (swap32(x,y): x.lanes[32:63] <->
// y.lanes[0:31]), no setprio, no launch-bounds cap, 256-thread blocks,
// one wave per matrix (all multi-matrix/persistent/big-block variants
// measured worse, R7-R19).

typedef unsigned int u32;
typedef __attribute__((ext_vector_type(8))) short bf16x8;
typedef __attribute__((ext_vector_type(16))) float f32x16;

#define FPAD 33   // f32 row stride of sym buffer: 33 mod 32 == 1 -> conflict-free

union U4 { u32 u[4]; bf16x8 v; };

__device__ __forceinline__ bf16x8 mk8(u32 a, u32 b, u32 c, u32 d) {
    U4 t; t.u[0] = a; t.u[1] = b; t.u[2] = c; t.u[3] = d; return t.v;
}

// pack bf16(x),bf16(y) (truncated) into one u32: low16 = x, high16 = y
__device__ __forceinline__ u32 pkt(float x, float y) {
    return __builtin_amdgcn_perm(__float_as_uint(y), __float_as_uint(x), 0x07060302u);
}

__device__ __forceinline__ float asfloat(u32 b) {
    union { u32 u; float f; } c; c.u = b; return c.f;
}

__device__ __forceinline__ f32x16 zero16() {
    f32x16 z;
#pragma unroll
    for (int i = 0; i < 16; ++i) z[i] = 0.f;
    return z;
}

// D-layout row of acc element i for this lane: (i&3) + 8*(i>>2) + 4*h; col = fr.
__device__ __forceinline__ float diagf(int i, int h, int fr) {
    return (((i & 3) + 8 * (i >> 2) + 4 * h) == fr) ? 1.f : 0.f;
}

struct Frag8 { u32 r[8]; };

// v_permlane32_swap_b32: x.lanes[32:63] <-> y.lanes[0:31]
__device__ __forceinline__ void swap32(u32& x, u32& y) {
    asm("v_permlane32_swap_b32 %0, %1" : "+v"(x), "+v"(y));
}

// packed-pair regs p[8] (D-layout pairs) -> B-fragment order.
__device__ __forceinline__ void xchg(const u32* p, Frag8& B) {
    { u32 x = p[0], y = p[2]; swap32(x, y); B.r[0] = x; B.r[2] = y; }
    { u32 x = p[1], y = p[3]; swap32(x, y); B.r[1] = x; B.r[3] = y; }
    { u32 x = p[4], y = p[6]; swap32(x, y); B.r[4] = x; B.r[6] = y; }
    { u32 x = p[5], y = p[7]; swap32(x, y); B.r[5] = x; B.r[7] = y; }
}

__device__ __forceinline__ void bconv(const f32x16& X, Frag8& B) {
    u32 p[8];
#pragma unroll
    for (int i = 0; i < 8; ++i) p[i] = pkt(X[2*i], X[2*i+1]);
    xchg(p, B);
}

__device__ __forceinline__ void bconv_s(const f32x16& X, float scale, Frag8& B) {
    u32 p[8];
#pragma unroll
    for (int i = 0; i < 8; ++i) p[i] = pkt(X[2*i] * scale, X[2*i+1] * scale);
    xchg(p, B);
}

__device__ __forceinline__ void bconv_split(const f32x16& X, Frag8& Bh, Frag8& Bl) {
    u32 p[8], q[8];
#pragma unroll
    for (int i = 0; i < 8; ++i) {
        const float x = X[2*i], y = X[2*i+1];
        p[i] = pkt(x, y);
        const float lx = x - asfloat(p[i] << 16);
        const float ly = y - asfloat(p[i] & 0xffff0000u);
        q[i] = pkt(lx, ly);
    }
    xchg(p, Bh);
    xchg(q, Bl);
}

__device__ __forceinline__ f32x16 MFMA1(const u32* a, const u32* b, f32x16 acc) {
    return __builtin_amdgcn_mfma_f32_32x32x16_bf16(
        mk8(a[0], a[1], a[2], a[3]), mk8(b[0], b[1], b[2], b[3]), acc, 0, 0, 0);
}

__device__ __forceinline__ f32x16 matmul(const Frag8& A, const Frag8& B, f32x16 acc) {
    acc = MFMA1(A.r,     B.r,     acc);   // k = 0..15
    acc = MFMA1(A.r + 4, B.r + 4, acc);   // k = 16..31
    return acc;
}

__global__ __launch_bounds__(256)
void leapfrog_fused(const float* __restrict__ Sg, const float* __restrict__ Pg,
                    const float* __restrict__ phig, const float* __restrict__ piphig,
                    float* __restrict__ out, int total)
{
    __shared__ __align__(16) float symb[4 * 32 * FPAD];

    // ---- XCD-aware chunked swizzle (bijective; 8 XCDs, round-robin HW
    //      mapping XCD = blockIdx % 8). Identity when nwg % 8 != 0. ----
    const int nwg = gridDim.x;
    int bid = blockIdx.x;
    if ((nwg & 7) == 0) {
        const int cpx = nwg >> 3;                 // chunk per XCD
        bid = (bid & 7) * cpx + (bid >> 3);
    }

    const int w  = threadIdx.x >> 6;
    const int l  = threadIdx.x & 63;
    const int bn = bid * 4 + w;
    if (bn >= total) return;            // wave-uniform; kernel has no barriers

    float* sy = symb + w * 32 * FPAD;

    const int fr = l & 31;
    const int h  = l >> 5;
    const size_t gbase = (size_t)bn * 1024;

    // ---- fragment loads straight from global; phi prefetched alongside ----
    const float* Srow = Sg + gbase + fr * 32 + h * 8;
    const float* Prow = Pg + gbase + fr * 32 + h * 8;
    const float4 sv[4] = { *(const float4*)(Srow +  0), *(const float4*)(Srow +  4),
                           *(const float4*)(Srow + 16), *(const float4*)(Srow + 20) };
    const float4 pv[4] = { *(const float4*)(Prow +  0), *(const float4*)(Prow +  4),
                           *(const float4*)(Prow + 16), *(const float4*)(Prow + 20) };
    // phi inputs: lanes 0-2 each handle one component in the epilogue
    float phc = 0.f, qhc = 0.f;
    if (l < 3) { phc = phig[3 * bn + l]; qhc = piphig[3 * bn + l]; }

    Frag8 FS, FSl, FP;
#pragma unroll
    for (int i = 0; i < 4; ++i) {
        const float4 s = sv[i];
        const float4 p = pv[i];
        const u32 ha = pkt(s.x, s.y);
        const u32 hb = pkt(s.z, s.w);
        FS.r[2*i]   = ha;
        FS.r[2*i+1] = hb;
        const float lx = s.x - asfloat(ha << 16);
        const float ly = s.y - asfloat(ha & 0xffff0000u);
        const float lz = s.z - asfloat(hb << 16);
        const float lw = s.w - asfloat(hb & 0xffff0000u);
        FSl.r[2*i]   = pkt(lx, ly);
        FSl.r[2*i+1] = pkt(lz, lw);
        FP.r[2*i]   = pkt(p.x, p.y);
        FP.r[2*i+1] = pkt(p.z, p.w);
    }

    // ---- U = S·P ; Ut = P·S (independent chains) ; H = U·U = S·P·S·P ----
    f32x16 U  = matmul(FS, FP, zero16());
    f32x16 Ut = matmul(FP, FS, zero16());
    Frag8 BU;  bconv(U,  BU);
    Frag8 BUt; bconv(Ut, BUt);              // as A-operand represents U
    f32x16 H = matmul(BUt, BU, zero16());

    // ---- M = 2DT·U − 2DT²·H ;  X3 = I + M/3 (f32 VALU, diag inline) ----
    f32x16 M, X;
#pragma unroll
    for (int i = 0; i < 16; ++i) {
        M[i] = 0.02f * U[i] - 2e-4f * H[i];
        X[i] = diagf(i, h, fr) + (1.0f / 3.0f) * M[i];
    }
    Frag8 FM; bconv(M, FM);                 // A-frag of M^T

    // ---- X2 = I + (1/2)·M^T·X3 ; X1 = I + M^T·X2 ----
    {
        Frag8 BX; bconv_s(X, 0.5f, BX);
        X = matmul(FM, BX, zero16());
#pragma unroll
        for (int i = 0; i < 16; ++i) X[i] += diagf(i, h, fr);
    }
    {
        Frag8 BX; bconv(X, BX);
        X = matmul(FM, BX, zero16());
#pragma unroll
        for (int i = 0; i < 16; ++i) X[i] += diagf(i, h, fr);
    }

    // ---- Y^T = S·X, hi/lo split, ONE serial accumulator ----
    Frag8 BE, BEl;
    bconv_split(X, BE, BEl);
    f32x16 Y = matmul(FS,  BEl, zero16());
    Y        = matmul(FSl, BE,  Y);
    Y        = matmul(FS,  BE,  Y);

    // ---- sym + eps·I via LDS bounce (fence REQUIRED — R15-class race) ----
#pragma unroll
    for (int i = 0; i < 16; ++i) {
        const int r = (i & 3) + 8 * (i >> 2) + 4 * h;
        sy[r * FPAD + fr] = Y[i];
    }
    __threadfence_block();                  // order bounce writes before reads
    const size_t obase = (size_t)bn * 1027;
#pragma unroll
    for (int k = 0; k < 16; ++k) {
        const int idx = k * 64 + l;
        const int r = idx >> 5, c = idx & 31;
        const float a = sy[r * FPAD + c];
        const float b = sy[c * FPAD + r];
        float v = 0.5f * (a + b);
        if (r == c) v += 1e-8f;
        __builtin_nontemporal_store(v, &out[obase + idx]);
    }

    // ---- fused phi retraction (lanes 0-2, double; floor-based mod 2pi) ----
    if (l < 3) {
        const double TWO_PI = 6.283185307179586476925287;
        const double PI_    = 3.141592653589793238462643;
        const double c0 = (double)__shfl(phc, 0, 64) + 0.01 * (double)__shfl(qhc, 0, 64);
        const double c1 = (double)__shfl(phc, 1, 64) + 0.01 * (double)__shfl(qhc, 1, 64);
        const double c2 = (double)__shfl(phc, 2, 64) + 0.01 * (double)__shfl(qhc, 2, 64);
        const double me = (l == 0) ? c0 : (l == 1) ? c1 : c2;
        const double theta = sqrt(c0 * c0 + c1 * c1 + c2 * c2);
        const double ts = theta > 1e-12 ? theta : 1e-12;
        const double k2 = floor(theta * (1.0 / TWO_PI));
        const double tw = theta - k2 * TWO_PI;          // fmod(theta, 2pi), theta >= 0
        double t, sgn;
        if (tw > PI_) { t = TWO_PI - tw; sgn = -1.0; }
        else          { t = tw;          sgn = 1.0;  }
        const double rmax = PI_ - 0.01;
        if (t > rmax) t = rmax;
        const double f = sgn * t / ts;
        __builtin_nontemporal_store((float)(me * f), &out[obase + 1024 + l]);
    }
}

extern "C" void kernel_launch(void* const* d_in, const int* in_sizes, int n_in,
                              void* d_out, int out_size, void* d_ws, size_t ws_size,
                              hipStream_t stream)
{
    const float* Sg     = (const float*)d_in[0];
    const float* Pg     = (const float*)d_in[1];
    const float* phig   = (const float*)d_in[2];
    const float* piphig = (const float*)d_in[3];
    float* out = (float*)d_out;

    const int total = in_sizes[0] / 1024;   // B*N = 32768 matrices

    leapfrog_fused<<<(total + 3) / 4, 256, 0, stream>>>(Sg, Pg, phig, piphig, out, total);
}